// Round 3
// baseline (430.736 us; speedup 1.0000x reference)
//
#include <hip/hip_runtime.h>

typedef unsigned short u16;
typedef unsigned int uint32;
typedef __bf16 bf16x8 __attribute__((ext_vector_type(8)));
typedef float f32x4 __attribute__((ext_vector_type(4)));

static constexpr int Gg = 64;
static constexpr int Nn = 2048;
static constexpr int Ee = 16384;
static constexpr int GN = Gg * Nn;   // 131072
static constexpr int GE = Gg * Ee;   // 1048576

__device__ __forceinline__ float u2f(u16 u) {
    return __uint_as_float(((uint32)u) << 16);
}
__device__ __forceinline__ u16 f2u(float f) {  // round-to-nearest-even bf16
    uint32 i = __float_as_uint(f);
    uint32 r = (i + 0x7FFFu + ((i >> 16) & 1u)) >> 16;
    return (u16)r;
}
__device__ __forceinline__ float lo16f(uint32 v) { return __uint_as_float(v << 16); }
__device__ __forceinline__ float hi16f(uint32 v) { return __uint_as_float(v & 0xffff0000u); }

// ---------------- setup kernels ----------------

__global__ void k_zero(int* __restrict__ p) {
    p[blockIdx.x * 256 + threadIdx.x] = 0;
}

__global__ void k_count(const int* __restrict__ ei, int* __restrict__ deg) {
    int e = blockIdx.x * 256 + threadIdx.x;
    atomicAdd(&deg[ei[GE + e]], 1);   // row 1 = dst (global ids)
}

__global__ void k_dis(const int* __restrict__ deg, float* __restrict__ dis,
                      float* __restrict__ invdeg) {
    int gid = blockIdx.x * 256 + threadIdx.x;
    float d = 1.0f + (float)deg[gid];
    dis[gid] = rsqrtf(d);
    invdeg[gid] = 1.0f / d;
}

// node-major counts + exclusive scan (1 block, 1024 threads, 2 nodes/thread)
__global__ void k_nm(const int* __restrict__ deg, int* __restrict__ pos_nm,
                     int* __restrict__ cur_nm) {
    int t = threadIdx.x;
    int i0 = 2 * t, i1 = 2 * t + 1;
    int c0 = 0, c1 = 0;
    #pragma unroll 8
    for (int g = 0; g < 64; ++g) {
        c0 += deg[g * Nn + i0];
        c1 += deg[g * Nn + i1];
    }
    __shared__ int ps[1024];
    ps[t] = c0 + c1; __syncthreads();
    for (int off = 1; off < 1024; off <<= 1) {
        int v = (t >= off) ? ps[t - off] : 0;
        __syncthreads();
        ps[t] += v;
        __syncthreads();
    }
    int base = ps[t] - (c0 + c1);
    pos_nm[i0] = base;      cur_nm[i0] = base;
    pos_nm[i1] = base + c0; cur_nm[i1] = base + c0;
    if (t == 1023) pos_nm[2048] = ps[1023];
}

__global__ void k_scatter_nm(const int* __restrict__ ei, const float* __restrict__ dis,
                             int* __restrict__ cur_nm, int2* __restrict__ nme) {
    int e = blockIdx.x * 256 + threadIdx.x;
    int s = ei[e];          // src gid
    int d = ei[GE + e];     // dst gid
    int il = d & (Nn - 1);  // local node
    int p = atomicAdd(&cur_nm[il], 1);
    nme[p] = make_int2(s, __float_as_int(dis[s] * dis[d]));
}

// transpose bottom half of Wm -> Wt[c][f] bf16
__global__ void k_trans(const float* __restrict__ Wm, u16* __restrict__ Wt) {
    int idx = blockIdx.x * 256 + threadIdx.x;   // 16384
    int f = idx >> 7, c = idx & 127;
    Wt[c * 128 + f] = f2u(Wm[(128 + f) * 128 + c]);
}

// A[g] = (ce @ Wm_top) + bm, ce = (x[center]*invdeg + incident edges) @ W1 + b1
__global__ void k_A(const float* __restrict__ x, const int* __restrict__ center,
                    const float* __restrict__ invdeg, const int* __restrict__ pos_nm,
                    const int2* __restrict__ nme,
                    const float* __restrict__ W1, const float* __restrict__ b1,
                    const float* __restrict__ Wm, const float* __restrict__ bm,
                    float* __restrict__ A) {
    int g = blockIdx.x, t = threadIdx.x;   // 128 threads
    __shared__ float cepre[128], ce[128];
    int cl = center[g];
    int cg = (g << 11) + cl;
    float v = x[cg * 128 + t] * invdeg[cg];
    int p0 = pos_nm[cl], p1 = pos_nm[cl + 1];
    for (int e = p0; e < p1; ++e) {          // usually empty (center has no edges)
        int2 m = nme[e];
        if ((m.x >> 11) == g) v += __int_as_float(m.y) * x[m.x * 128 + t];
    }
    cepre[t] = v; __syncthreads();
    float a = b1[t];
    #pragma unroll 8
    for (int f = 0; f < 128; ++f) a += cepre[f] * W1[f * 128 + t];
    ce[t] = a; __syncthreads();
    float o = bm[t];
    #pragma unroll 8
    for (int h = 0; h < 128; ++h) o += ce[h] * Wm[h * 128 + t];
    A[g * 128 + t] = o;
}

// ---------------- mask + y GEMM (MFMA), writes packed xy ----------------
// xy row (256 u16): group k (u16[4k..4k+4)) = { y[2k], y[2k+1], x[2k], x[2k+1] } bf16
__global__ __launch_bounds__(256) void k_masky(const float* __restrict__ x,
                                               const u16* __restrict__ Wt,
                                               const float* __restrict__ A,
                                               u16* __restrict__ xy) {
    __shared__ u16 sWt[128 * 128];
    __shared__ float sA[128];
    __shared__ float sC[4][16 * 128];
    int t = threadIdx.x;
    int rowbase = blockIdx.x * 64;
    int g = rowbase >> 11;

    #pragma unroll
    for (int j = 0; j < 8; ++j)
        ((uint4*)sWt)[j * 256 + t] = ((const uint4*)Wt)[j * 256 + t];
    if (t < 128) sA[t] = A[g * 128 + t];
    __syncthreads();

    int w = t >> 6, l = t & 63;
    int row0 = rowbase + w * 16;
    int lm = l & 15, lq = l >> 4;

    f32x4 acc[8] = {};
    #pragma unroll
    for (int ks = 0; ks < 4; ++ks) {
        const float* xp = x + (row0 + lm) * 128 + ks * 32 + lq * 8;
        float4 x0 = *(const float4*)(xp);
        float4 x1 = *(const float4*)(xp + 4);
        union { u16 u[8]; bf16x8 v; } af;
        af.u[0] = f2u(x0.x); af.u[1] = f2u(x0.y); af.u[2] = f2u(x0.z); af.u[3] = f2u(x0.w);
        af.u[4] = f2u(x1.x); af.u[5] = f2u(x1.y); af.u[6] = f2u(x1.z); af.u[7] = f2u(x1.w);
        #pragma unroll
        for (int ct = 0; ct < 8; ++ct) {
            bf16x8 b = *reinterpret_cast<const bf16x8*>(sWt + (ct * 16 + lm) * 128 + ks * 32 + lq * 8);
            acc[ct] = __builtin_amdgcn_mfma_f32_16x16x32_bf16(af.v, b, acc[ct], 0, 0, 0);
        }
    }

    float* myC = &sC[w][0];
    #pragma unroll
    for (int ct = 0; ct < 8; ++ct)
        #pragma unroll
        for (int r = 0; r < 4; ++r)
            myC[(lq * 4 + r) * 128 + ct * 16 + lm] = acc[ct][r];
    __syncthreads();

    int lr = l >> 2;
    int cc = (l & 3) * 32;
    int grow = row0 + lr;
    const float* xr = x + grow * 128 + cc;
    u16* orow = xy + grow * 256;
    #pragma unroll
    for (int j = 0; j < 4; ++j) {
        int c0 = cc + j * 8;
        float4 ca = *(const float4*)(myC + lr * 128 + c0);
        float4 cb = *(const float4*)(myC + lr * 128 + c0 + 4);
        float4 xa = *(const float4*)(xr + j * 8);
        float4 xd = *(const float4*)(xr + j * 8 + 4);
        float m0 = fmaxf(ca.x + sA[c0 + 0], 0.f) * xa.x;
        float m1 = fmaxf(ca.y + sA[c0 + 1], 0.f) * xa.y;
        float m2 = fmaxf(ca.z + sA[c0 + 2], 0.f) * xa.z;
        float m3 = fmaxf(ca.w + sA[c0 + 3], 0.f) * xa.w;
        float m4 = fmaxf(cb.x + sA[c0 + 4], 0.f) * xd.x;
        float m5 = fmaxf(cb.y + sA[c0 + 5], 0.f) * xd.y;
        float m6 = fmaxf(cb.z + sA[c0 + 6], 0.f) * xd.z;
        float m7 = fmaxf(cb.w + sA[c0 + 7], 0.f) * xd.w;
        uint4 q1, q2;
        q1.x = (uint32)f2u(m0) | ((uint32)f2u(m1) << 16);
        q1.y = (uint32)f2u(xa.x) | ((uint32)f2u(xa.y) << 16);
        q1.z = (uint32)f2u(m2) | ((uint32)f2u(m3) << 16);
        q1.w = (uint32)f2u(xa.z) | ((uint32)f2u(xa.w) << 16);
        q2.x = (uint32)f2u(m4) | ((uint32)f2u(m5) << 16);
        q2.y = (uint32)f2u(xd.x) | ((uint32)f2u(xd.y) << 16);
        q2.z = (uint32)f2u(m6) | ((uint32)f2u(m7) << 16);
        q2.w = (uint32)f2u(xd.z) | ((uint32)f2u(xd.w) << 16);
        *(uint4*)(orow + 2 * c0) = q1;
        *(uint4*)(orow + 2 * c0 + 8) = q2;
    }
}

// ---------------- flat gather + graph-mean + output GEMMs ----------------
__global__ __launch_bounds__(256) void k_prop(const u16* __restrict__ xy,
                                              const float* __restrict__ invdeg,
                                              const int* __restrict__ pos_nm,
                                              const int2* __restrict__ nme,
                                              const float* __restrict__ W2, const float* __restrict__ b2,
                                              const float* __restrict__ W3, const float* __restrict__ b3,
                                              float* __restrict__ out) {
    int i = blockIdx.x;               // node 0..2046
    int t = threadIdx.x, w = t >> 6, l = t & 63;
    float z0 = 0.f, z1 = 0.f, zx0 = 0.f, zx1 = 0.f;

    // self terms: graphs w, w+4, ...
    #pragma unroll 4
    for (int g = w; g < 64; g += 4) {
        int gid = (g << 11) + i;
        float cf = invdeg[gid];
        uint2 v = *(const uint2*)(xy + gid * 256 + 4 * l);
        z0 += cf * lo16f(v.x);  z1 += cf * hi16f(v.x);
        zx0 += cf * lo16f(v.y); zx1 += cf * hi16f(v.y);
    }

    // edge entries: flat node-major list, waves interleaved
    int p0 = pos_nm[i], p1 = pos_nm[i + 1];
    int j = p0 + w;
    while (j + 4 < p1) {
        int2 m0 = nme[j];
        int2 m1 = nme[j + 4];
        uint2 v0 = *(const uint2*)(xy + m0.x * 256 + 4 * l);
        uint2 v1 = *(const uint2*)(xy + m1.x * 256 + 4 * l);
        float c0 = __int_as_float(m0.y), c1 = __int_as_float(m1.y);
        z0 += c0 * lo16f(v0.x);  z1 += c0 * hi16f(v0.x);
        zx0 += c0 * lo16f(v0.y); zx1 += c0 * hi16f(v0.y);
        z0 += c1 * lo16f(v1.x);  z1 += c1 * hi16f(v1.x);
        zx0 += c1 * lo16f(v1.y); zx1 += c1 * hi16f(v1.y);
        j += 8;
    }
    if (j < p1) {
        int2 m0 = nme[j];
        uint2 v0 = *(const uint2*)(xy + m0.x * 256 + 4 * l);
        float c0 = __int_as_float(m0.y);
        z0 += c0 * lo16f(v0.x);  z1 += c0 * hi16f(v0.x);
        zx0 += c0 * lo16f(v0.y); zx1 += c0 * hi16f(v0.y);
    }

    __shared__ float rz[4][128], rx[4][128], zm[128], zxm[128];
    rz[w][2 * l] = z0; rz[w][2 * l + 1] = z1;
    rx[w][2 * l] = zx0; rx[w][2 * l + 1] = zx1;
    __syncthreads();
    if (t < 128) {
        zm[t]  = (rz[0][t] + rz[1][t] + rz[2][t] + rz[3][t]) * (1.0f / 64.0f);
        zxm[t] = (rx[0][t] + rx[1][t] + rx[2][t] + rx[3][t]) * (1.0f / 64.0f);
    }
    __syncthreads();
    int c = t & 127;
    if (t < 128) {
        float acc = b2[c];
        #pragma unroll 8
        for (int f = 0; f < 128; ++f) acc += zm[f] * W2[f * 128 + c];
        out[i * 128 + c] = acc;
    } else {
        float acc = b3[c];
        #pragma unroll 8
        for (int f = 0; f < 128; ++f) acc += (zxm[f] - zm[f]) * W3[f * 128 + c];
        out[2047 * 128 + i * 128 + c] = acc;
    }
}

// ---------------- launch ----------------

extern "C" void kernel_launch(void* const* d_in, const int* in_sizes, int n_in,
                              void* d_out, int out_size, void* d_ws, size_t ws_size,
                              hipStream_t stream) {
    const float* x    = (const float*)d_in[0];
    const int* ei     = (const int*)d_in[1];
    const int* center = (const int*)d_in[3];
    const float* W1 = (const float*)d_in[4];
    const float* b1 = (const float*)d_in[5];
    const float* W2 = (const float*)d_in[6];
    const float* b2 = (const float*)d_in[7];
    const float* W3 = (const float*)d_in[8];
    const float* b3 = (const float*)d_in[9];
    const float* Wm = (const float*)d_in[10];
    const float* bm = (const float*)d_in[11];
    float* out = (float*)d_out;

    char* ws = (char*)d_ws;
    int*   degc   = (int*)(ws + 0);            // 512 KB
    float* dis    = (float*)(ws + 524288);     // 512 KB
    float* invdeg = (float*)(ws + 1048576);    // 512 KB
    int*   pos_nm = (int*)(ws + 1572864);      // 16 KB (2049 used)
    int*   cur_nm = (int*)(ws + 1589248);      // 16 KB
    float* A      = (float*)(ws + 1605632);    // 32 KB
    u16*   Wt     = (u16*)(ws + 1638400);      // 32 KB
    int2*  nme    = (int2*)(ws + 1671168);     // 8 MB
    u16*   xy     = (u16*)(ws + 10059776);     // 67 MB

    k_zero<<<dim3(GN / 256), dim3(256), 0, stream>>>(degc);
    k_count<<<dim3(GE / 256), dim3(256), 0, stream>>>(ei, degc);
    k_dis<<<dim3(GN / 256), dim3(256), 0, stream>>>(degc, dis, invdeg);
    k_nm<<<dim3(1), dim3(1024), 0, stream>>>(degc, pos_nm, cur_nm);
    k_scatter_nm<<<dim3(GE / 256), dim3(256), 0, stream>>>(ei, dis, cur_nm, nme);
    k_trans<<<dim3(64), dim3(256), 0, stream>>>(Wm, Wt);
    k_A<<<dim3(Gg), dim3(128), 0, stream>>>(x, center, invdeg, pos_nm, nme, W1, b1, Wm, bm, A);
    k_masky<<<dim3(GN / 64), dim3(256), 0, stream>>>(x, Wt, A, xy);
    k_prop<<<dim3(Nn - 1), dim3(256), 0, stream>>>(xy, invdeg, pos_nm, nme, W2, b2, W3, b3, out);
}

// Round 4
// 357.546 us; speedup vs baseline: 1.2047x; 1.2047x over previous
//
#include <hip/hip_runtime.h>

typedef unsigned short u16;
typedef unsigned int uint32;
typedef __bf16 bf16x8 __attribute__((ext_vector_type(8)));
typedef float f32x4 __attribute__((ext_vector_type(4)));

static constexpr int Gg = 64;
static constexpr int Nn = 2048;
static constexpr int Ee = 16384;
static constexpr int GN = Gg * Nn;   // 131072
static constexpr int GE = Gg * Ee;   // 1048576

__device__ __forceinline__ u16 f2u(float f) {  // round-to-nearest-even bf16
    uint32 i = __float_as_uint(f);
    uint32 r = (i + 0x7FFFu + ((i >> 16) & 1u)) >> 16;
    return (u16)r;
}
__device__ __forceinline__ float lo16f(uint32 v) { return __uint_as_float(v << 16); }
__device__ __forceinline__ float hi16f(uint32 v) { return __uint_as_float(v & 0xffff0000u); }

// ---------------- setup kernels ----------------

__global__ void k_zero(int* __restrict__ p) {
    p[blockIdx.x * 256 + threadIdx.x] = 0;
}

__global__ void k_count(const int* __restrict__ ei, int* __restrict__ deg) {
    int e = blockIdx.x * 256 + threadIdx.x;
    atomicAdd(&deg[ei[GE + e]], 1);   // row 1 = dst (global ids)
}

__global__ void k_dis(const int* __restrict__ deg, float* __restrict__ dis,
                      float* __restrict__ invdeg) {
    int gid = blockIdx.x * 256 + threadIdx.x;
    float d = 1.0f + (float)deg[gid];
    dis[gid] = rsqrtf(d);
    invdeg[gid] = 1.0f / d;
}

// tot[i] = sum_g deg[g][i]
__global__ void k_colsum(const int* __restrict__ deg, int* __restrict__ tot) {
    int i = blockIdx.x * 256 + threadIdx.x;
    int c = 0;
    #pragma unroll 8
    for (int g = 0; g < 64; ++g) c += deg[(g << 11) + i];
    tot[i] = c;
}

// exclusive scan of tot -> pos_nm (1 block, 1024 threads, 2 nodes/thread)
__global__ void k_scan_nm(const int* __restrict__ tot, int* __restrict__ pos_nm) {
    int t = threadIdx.x;
    int c0 = tot[2 * t], c1 = tot[2 * t + 1];
    __shared__ int ps[1024];
    ps[t] = c0 + c1; __syncthreads();
    for (int off = 1; off < 1024; off <<= 1) {
        int v = (t >= off) ? ps[t - off] : 0;
        __syncthreads();
        ps[t] += v;
        __syncthreads();
    }
    int base = ps[t] - (c0 + c1);
    pos_nm[2 * t] = base;
    pos_nm[2 * t + 1] = base + c0;
    if (t == 1023) pos_nm[2048] = ps[1023];
}

// cur[g][i] = pos_nm[i] + sum_{g'<g} deg[g'][i]  (deterministic group starts)
__global__ void k_start(const int* __restrict__ deg, const int* __restrict__ pos_nm,
                        int* __restrict__ cur) {
    int i = blockIdx.x * 256 + threadIdx.x;
    int run = pos_nm[i];
    #pragma unroll 8
    for (int g = 0; g < 64; ++g) {
        cur[(g << 11) + i] = run;
        run += deg[(g << 11) + i];
    }
}

// rank-within-(g,i) atomic only: 131072 cursors, ~8 collisions each
__global__ void k_scatter(const int* __restrict__ ei, const float* __restrict__ dis,
                          int* __restrict__ cur, int2* __restrict__ nme) {
    int e = blockIdx.x * 256 + threadIdx.x;
    int s = ei[e];          // src gid
    int d = ei[GE + e];     // dst gid
    int p = atomicAdd(&cur[d], 1);
    nme[p] = make_int2(s, __float_as_int(dis[s] * dis[d]));
}

// transpose bottom half of Wm -> Wt[c][f] bf16
__global__ void k_trans(const float* __restrict__ Wm, u16* __restrict__ Wt) {
    int idx = blockIdx.x * 256 + threadIdx.x;   // 16384
    int f = idx >> 7, c = idx & 127;
    Wt[c * 128 + f] = f2u(Wm[(128 + f) * 128 + c]);
}

// A[g] = (ce @ Wm_top) + bm, ce = (x[center]*invdeg + incident edges) @ W1 + b1
__global__ void k_A(const float* __restrict__ x, const int* __restrict__ center,
                    const float* __restrict__ invdeg, const int* __restrict__ pos_nm,
                    const int2* __restrict__ nme,
                    const float* __restrict__ W1, const float* __restrict__ b1,
                    const float* __restrict__ Wm, const float* __restrict__ bm,
                    float* __restrict__ A) {
    int g = blockIdx.x, t = threadIdx.x;   // 128 threads
    __shared__ float cepre[128], ce[128];
    int cl = center[g];
    int cg = (g << 11) + cl;
    float v = x[cg * 128 + t] * invdeg[cg];
    int p0 = pos_nm[cl], p1 = pos_nm[cl + 1];
    for (int e = p0; e < p1; ++e) {          // usually empty (center has no in-edges)
        int2 m = nme[e];
        if ((m.x >> 11) == g) v += __int_as_float(m.y) * x[m.x * 128 + t];
    }
    cepre[t] = v; __syncthreads();
    float a = b1[t];
    #pragma unroll 8
    for (int f = 0; f < 128; ++f) a += cepre[f] * W1[f * 128 + t];
    ce[t] = a; __syncthreads();
    float o = bm[t];
    #pragma unroll 8
    for (int h = 0; h < 128; ++h) o += ce[h] * Wm[h * 128 + t];
    A[g * 128 + t] = o;
}

// ---------------- mask + y GEMM (MFMA), writes packed xy ----------------
// xy row (256 u16): group k (u16[4k..4k+4)) = { y[2k], y[2k+1], x[2k], x[2k+1] } bf16
__global__ __launch_bounds__(256) void k_masky(const float* __restrict__ x,
                                               const u16* __restrict__ Wt,
                                               const float* __restrict__ A,
                                               u16* __restrict__ xy) {
    __shared__ u16 sWt[128 * 128];
    __shared__ float sA[128];
    __shared__ float sC[4][16 * 128];
    int t = threadIdx.x;
    int rowbase = blockIdx.x * 64;
    int g = rowbase >> 11;

    #pragma unroll
    for (int j = 0; j < 8; ++j)
        ((uint4*)sWt)[j * 256 + t] = ((const uint4*)Wt)[j * 256 + t];
    if (t < 128) sA[t] = A[g * 128 + t];
    __syncthreads();

    int w = t >> 6, l = t & 63;
    int row0 = rowbase + w * 16;
    int lm = l & 15, lq = l >> 4;

    f32x4 acc[8] = {};
    #pragma unroll
    for (int ks = 0; ks < 4; ++ks) {
        const float* xp = x + (row0 + lm) * 128 + ks * 32 + lq * 8;
        float4 x0 = *(const float4*)(xp);
        float4 x1 = *(const float4*)(xp + 4);
        union { u16 u[8]; bf16x8 v; } af;
        af.u[0] = f2u(x0.x); af.u[1] = f2u(x0.y); af.u[2] = f2u(x0.z); af.u[3] = f2u(x0.w);
        af.u[4] = f2u(x1.x); af.u[5] = f2u(x1.y); af.u[6] = f2u(x1.z); af.u[7] = f2u(x1.w);
        #pragma unroll
        for (int ct = 0; ct < 8; ++ct) {
            bf16x8 b = *reinterpret_cast<const bf16x8*>(sWt + (ct * 16 + lm) * 128 + ks * 32 + lq * 8);
            acc[ct] = __builtin_amdgcn_mfma_f32_16x16x32_bf16(af.v, b, acc[ct], 0, 0, 0);
        }
    }

    float* myC = &sC[w][0];
    #pragma unroll
    for (int ct = 0; ct < 8; ++ct)
        #pragma unroll
        for (int r = 0; r < 4; ++r)
            myC[(lq * 4 + r) * 128 + ct * 16 + lm] = acc[ct][r];
    __syncthreads();

    int lr = l >> 2;
    int cc = (l & 3) * 32;
    int grow = row0 + lr;
    const float* xr = x + grow * 128 + cc;
    u16* orow = xy + grow * 256;
    #pragma unroll
    for (int j = 0; j < 4; ++j) {
        int c0 = cc + j * 8;
        float4 ca = *(const float4*)(myC + lr * 128 + c0);
        float4 cb = *(const float4*)(myC + lr * 128 + c0 + 4);
        float4 xa = *(const float4*)(xr + j * 8);
        float4 xd = *(const float4*)(xr + j * 8 + 4);
        float m0 = fmaxf(ca.x + sA[c0 + 0], 0.f) * xa.x;
        float m1 = fmaxf(ca.y + sA[c0 + 1], 0.f) * xa.y;
        float m2 = fmaxf(ca.z + sA[c0 + 2], 0.f) * xa.z;
        float m3 = fmaxf(ca.w + sA[c0 + 3], 0.f) * xa.w;
        float m4 = fmaxf(cb.x + sA[c0 + 4], 0.f) * xd.x;
        float m5 = fmaxf(cb.y + sA[c0 + 5], 0.f) * xd.y;
        float m6 = fmaxf(cb.z + sA[c0 + 6], 0.f) * xd.z;
        float m7 = fmaxf(cb.w + sA[c0 + 7], 0.f) * xd.w;
        uint4 q1, q2;
        q1.x = (uint32)f2u(m0) | ((uint32)f2u(m1) << 16);
        q1.y = (uint32)f2u(xa.x) | ((uint32)f2u(xa.y) << 16);
        q1.z = (uint32)f2u(m2) | ((uint32)f2u(m3) << 16);
        q1.w = (uint32)f2u(xa.z) | ((uint32)f2u(xa.w) << 16);
        q2.x = (uint32)f2u(m4) | ((uint32)f2u(m5) << 16);
        q2.y = (uint32)f2u(xd.x) | ((uint32)f2u(xd.y) << 16);
        q2.z = (uint32)f2u(m6) | ((uint32)f2u(m7) << 16);
        q2.w = (uint32)f2u(xd.z) | ((uint32)f2u(xd.w) << 16);
        *(uint4*)(orow + 2 * c0) = q1;
        *(uint4*)(orow + 2 * c0 + 8) = q2;
    }
}

// ---------------- flat gather + graph-mean + output GEMMs ----------------
__global__ __launch_bounds__(256) void k_prop(const u16* __restrict__ xy,
                                              const float* __restrict__ invdeg,
                                              const int* __restrict__ pos_nm,
                                              const int2* __restrict__ nme,
                                              const float* __restrict__ W2, const float* __restrict__ b2,
                                              const float* __restrict__ W3, const float* __restrict__ b3,
                                              float* __restrict__ out) {
    int i = blockIdx.x;               // node 0..2046
    int t = threadIdx.x, w = t >> 6, l = t & 63;
    float z0 = 0.f, z1 = 0.f, zx0 = 0.f, zx1 = 0.f;

    // self terms: graphs w, w+4, ... (unrolled, 4 loads in flight)
    #pragma unroll
    for (int gb = 0; gb < 64; gb += 16) {
        int g0 = gb + w;
        float c0 = invdeg[(g0 << 11) + i],        c1 = invdeg[((g0 + 4) << 11) + i];
        float c2 = invdeg[((g0 + 8) << 11) + i],  c3 = invdeg[((g0 + 12) << 11) + i];
        uint2 v0 = *(const uint2*)(xy + ((g0 << 11) + i) * 256 + 4 * l);
        uint2 v1 = *(const uint2*)(xy + (((g0 + 4) << 11) + i) * 256 + 4 * l);
        uint2 v2 = *(const uint2*)(xy + (((g0 + 8) << 11) + i) * 256 + 4 * l);
        uint2 v3 = *(const uint2*)(xy + (((g0 + 12) << 11) + i) * 256 + 4 * l);
        z0 += c0 * lo16f(v0.x);  z1 += c0 * hi16f(v0.x);
        zx0 += c0 * lo16f(v0.y); zx1 += c0 * hi16f(v0.y);
        z0 += c1 * lo16f(v1.x);  z1 += c1 * hi16f(v1.x);
        zx0 += c1 * lo16f(v1.y); zx1 += c1 * hi16f(v1.y);
        z0 += c2 * lo16f(v2.x);  z1 += c2 * hi16f(v2.x);
        zx0 += c2 * lo16f(v2.y); zx1 += c2 * hi16f(v2.y);
        z0 += c3 * lo16f(v3.x);  z1 += c3 * hi16f(v3.x);
        zx0 += c3 * lo16f(v3.y); zx1 += c3 * hi16f(v3.y);
    }

    // edge entries: flat node-major list, waves interleaved stride 4, pipeline depth 4
    int p0 = pos_nm[i], p1 = pos_nm[i + 1];
    int j = p0 + w;
    for (; j + 12 < p1; j += 16) {
        int2 m0 = nme[j];
        int2 m1 = nme[j + 4];
        int2 m2 = nme[j + 8];
        int2 m3 = nme[j + 12];
        uint2 v0 = *(const uint2*)(xy + m0.x * 256 + 4 * l);
        uint2 v1 = *(const uint2*)(xy + m1.x * 256 + 4 * l);
        uint2 v2 = *(const uint2*)(xy + m2.x * 256 + 4 * l);
        uint2 v3 = *(const uint2*)(xy + m3.x * 256 + 4 * l);
        float c0 = __int_as_float(m0.y), c1 = __int_as_float(m1.y);
        float c2 = __int_as_float(m2.y), c3 = __int_as_float(m3.y);
        z0 += c0 * lo16f(v0.x);  z1 += c0 * hi16f(v0.x);
        zx0 += c0 * lo16f(v0.y); zx1 += c0 * hi16f(v0.y);
        z0 += c1 * lo16f(v1.x);  z1 += c1 * hi16f(v1.x);
        zx0 += c1 * lo16f(v1.y); zx1 += c1 * hi16f(v1.y);
        z0 += c2 * lo16f(v2.x);  z1 += c2 * hi16f(v2.x);
        zx0 += c2 * lo16f(v2.y); zx1 += c2 * hi16f(v2.y);
        z0 += c3 * lo16f(v3.x);  z1 += c3 * hi16f(v3.x);
        zx0 += c3 * lo16f(v3.y); zx1 += c3 * hi16f(v3.y);
    }
    for (; j < p1; j += 4) {
        int2 m0 = nme[j];
        uint2 v0 = *(const uint2*)(xy + m0.x * 256 + 4 * l);
        float c0 = __int_as_float(m0.y);
        z0 += c0 * lo16f(v0.x);  z1 += c0 * hi16f(v0.x);
        zx0 += c0 * lo16f(v0.y); zx1 += c0 * hi16f(v0.y);
    }

    __shared__ float rz[4][128], rx[4][128], zm[128], zxm[128];
    rz[w][2 * l] = z0; rz[w][2 * l + 1] = z1;
    rx[w][2 * l] = zx0; rx[w][2 * l + 1] = zx1;
    __syncthreads();
    if (t < 128) {
        zm[t]  = (rz[0][t] + rz[1][t] + rz[2][t] + rz[3][t]) * (1.0f / 64.0f);
        zxm[t] = (rx[0][t] + rx[1][t] + rx[2][t] + rx[3][t]) * (1.0f / 64.0f);
    }
    __syncthreads();
    int c = t & 127;
    if (t < 128) {
        float acc = b2[c];
        #pragma unroll 8
        for (int f = 0; f < 128; ++f) acc += zm[f] * W2[f * 128 + c];
        out[i * 128 + c] = acc;
    } else {
        float acc = b3[c];
        #pragma unroll 8
        for (int f = 0; f < 128; ++f) acc += (zxm[f] - zm[f]) * W3[f * 128 + c];
        out[2047 * 128 + i * 128 + c] = acc;
    }
}

// ---------------- launch ----------------

extern "C" void kernel_launch(void* const* d_in, const int* in_sizes, int n_in,
                              void* d_out, int out_size, void* d_ws, size_t ws_size,
                              hipStream_t stream) {
    const float* x    = (const float*)d_in[0];
    const int* ei     = (const int*)d_in[1];
    const int* center = (const int*)d_in[3];
    const float* W1 = (const float*)d_in[4];
    const float* b1 = (const float*)d_in[5];
    const float* W2 = (const float*)d_in[6];
    const float* b2 = (const float*)d_in[7];
    const float* W3 = (const float*)d_in[8];
    const float* b3 = (const float*)d_in[9];
    const float* Wm = (const float*)d_in[10];
    const float* bm = (const float*)d_in[11];
    float* out = (float*)d_out;

    char* ws = (char*)d_ws;
    int*   degc   = (int*)(ws + 0);            // 512 KB
    float* dis    = (float*)(ws + 524288);     // 512 KB
    float* invdeg = (float*)(ws + 1048576);    // 512 KB
    int*   tot    = (int*)(ws + 1572864);      // 8 KB
    int*   pos_nm = (int*)(ws + 1581056);      // 16 KB (2049 used)
    int*   cur    = (int*)(ws + 1597440);      // 512 KB
    float* A      = (float*)(ws + 2121728);    // 32 KB
    u16*   Wt     = (u16*)(ws + 2154496);      // 32 KB
    int2*  nme    = (int2*)(ws + 2187264);     // 8 MB
    u16*   xy     = (u16*)(ws + 10575872);     // 67 MB

    k_zero<<<dim3(GN / 256), dim3(256), 0, stream>>>(degc);
    k_count<<<dim3(GE / 256), dim3(256), 0, stream>>>(ei, degc);
    k_dis<<<dim3(GN / 256), dim3(256), 0, stream>>>(degc, dis, invdeg);
    k_colsum<<<dim3(Nn / 256), dim3(256), 0, stream>>>(degc, tot);
    k_scan_nm<<<dim3(1), dim3(1024), 0, stream>>>(tot, pos_nm);
    k_start<<<dim3(Nn / 256), dim3(256), 0, stream>>>(degc, pos_nm, cur);
    k_scatter<<<dim3(GE / 256), dim3(256), 0, stream>>>(ei, dis, cur, nme);
    k_trans<<<dim3(64), dim3(256), 0, stream>>>(Wm, Wt);
    k_A<<<dim3(Gg), dim3(128), 0, stream>>>(x, center, invdeg, pos_nm, nme, W1, b1, Wm, bm, A);
    k_masky<<<dim3(GN / 64), dim3(256), 0, stream>>>(x, Wt, A, xy);
    k_prop<<<dim3(Nn - 1), dim3(256), 0, stream>>>(xy, invdeg, pos_nm, nme, W2, b2, W3, b3, out);
}